// Round 5
// baseline (946.189 us; speedup 1.0000x reference)
//
#include <hip/hip_runtime.h>
#include <hip/hip_bf16.h>

typedef __bf16 bf16;
typedef __bf16 bf16x8 __attribute__((ext_vector_type(8)));
typedef __bf16 bf16x4 __attribute__((ext_vector_type(4)));
typedef float  f32x4  __attribute__((ext_vector_type(4)));

#define DIM   1024
#define SEQ   2048
#define BATCH 8
#define NROWS (BATCH * SEQ)
#define HID   4096

// ---------------- async global->LDS (16B/lane) ----------------
__device__ __forceinline__ void async_ld16(const bf16* g, bf16* l) {
    __builtin_amdgcn_global_load_lds(
        (__attribute__((address_space(1))) void*)(g),
        (__attribute__((address_space(3))) void*)(l),
        16, 0, 0);
}

__device__ __forceinline__ f32x4 mfma16(bf16x8 a, bf16x8 b, f32x4 c) {
    return __builtin_amdgcn_mfma_f32_16x16x32_bf16(a, b, c, 0, 0, 0);
}

// =====================================================================
// 256x256-tile, BK=64, 512-thread (8-wave) GEMM (v5).
//   C[M,N] = A[M,K] @ Bt[N,K]^T  (+epilogue variants)
//
// v5 theory: rounds 1-4 all pinned MfmaUtil at 27-30% because every
// schedule put `s_waitcnt lgkmcnt(0)` at phase heads, draining the LDS
// queue each phase -> LDS-pipe time (~2.8k cyc/K-tile/CU) ADDED to
// matrix-pipe time (~2.5k) instead of overlapping.  Our LDS reads are
// compiler-visible addrspace(3) loads, so the compiler inserts exact
// counted lgkmcnt(N) waits on its own (m97 asm evidence) — the manual
// drains were only ever needed for inline-asm ds_reads (rule #18).
//
// v5 structure per K-tile (ONE barrier, ONE vmcnt):
//   vmcnt(0)            // outstanding == exactly this tile's 8 loads
//   s_barrier           // all waves' stages of this tile resident
//   stage (T+1).B -> other buf          (4 global_load_lds / thread)
//   ds_read bg0,bg1,afA (16 b128)       (compiler-counted waits)
//   32 MFMA  (quadrants (0,0),(0,1))    (setprio 1)
//   stage (T+1).A -> other buf          (4 loads)
//   ds_read afB (8 b128)
//   32 MFMA  (quadrants (1,0),(1,1))
// ds_reads issue ahead of / between MFMAs; the LDS pipe drains UNDER the
// MFMA clusters; next tile's vmcnt(0) is reached with reads retired.
//
// Cross-wave hazards with the single barrier (all verified):
//  - reads of tile T (post-BAR) need all waves' T stages resident:
//    each wave retires its own loads via vmcnt(0) pre-BAR -> BAR ✓
//  - stage (T+1).B/A overwrites tile (T-1) slots: every (T-1) read is
//    consumed by a (T-1) MFMA, which precedes this BAR in program order
//    on every wave -> slots dead chip-wide ✓
// In-flight: (T+1).B staged S(T) gated S(T+1) (~1 tile); (T+1).A staged
// mid-tile, gated S(T+1) (~half tile) — both >= HBM latency at target.
// Tail: stage index clamps to NT-1 -> dead-slot rewrite, never read.
// LDS chunk-XOR swizzle (phys16B = data16B ^ (row&7)); 0 bank conflicts.
// BIASMODE: 0 none, 1 bias[n], 2 bias[m];  SCORE: scale+causal, skip
// fully-masked tiles;  PV: causal K-stop (kEnd = m0+256).
// =====================================================================
template<int OUTF32, int BIASMODE, int RESID, int GELU, int SCORE, int PV>
__global__ __launch_bounds__(512, 2) void gemm256_kernel(
    const bf16* __restrict__ A, size_t aB,
    const bf16* __restrict__ B, size_t bB,
    void* __restrict__ Cv, size_t cB,
    const float* __restrict__ bias,
    const float* __restrict__ resid,
    int M, int N, int K, float scale)
{
    __shared__ alignas(16) bf16 LA[2 * 2 * 8192];   // [db][half][128*64]
    __shared__ alignas(16) bf16 LB[2 * 2 * 8192];

    // bijective XCD-chunk swizzle of the linear tile id (m204 formula)
    const int gx = gridDim.x;
    int lin = blockIdx.y * gx + blockIdx.x;
    {
        const int nwg = gx * gridDim.y;
        const int q = nwg >> 3, r = nwg & 7;
        const int xcd = lin & 7, o = lin >> 3;
        lin = (xcd < r ? xcd * (q + 1) : r * (q + 1) + (xcd - r) * q) + o;
    }
    const int m0 = (lin / gx) * 256;
    const int n0 = (lin % gx) * 256;
    if (SCORE && n0 >= m0 + 256) return;   // fully-masked tile

    const int z = blockIdx.z;
    A += (size_t)z * aB;
    B += (size_t)z * bB;

    const int t    = threadIdx.x;
    const int lane = t & 63;
    const int wave = t >> 6;        // 0..7
    const int wm   = wave >> 2;     // 0..1  -> A rows wm*128..+128
    const int wn   = wave & 3;      // 0..3  -> B rows wn*64..+64

    const int kEnd = PV ? (m0 + 256) : K;
    const int NT   = kEnd >> 6;     // K-tiles of 64; always even, >= 4 here

    // ---- staging addresses: thread t covers flat 16B-chunk of a half
    const int srow = t >> 3;                              // 0..63
    const int sd   = ((t & 7) ^ (srow & 7)) * 8;          // inverse-swizzled data col
    const bf16* gA = A + (size_t)(m0 + srow) * (size_t)K + sd;
    const bf16* gB = B + (size_t)(n0 + srow) * (size_t)K + sd;
    bf16* const lA = LA + wave * 512;                     // + lane*16B by HW
    bf16* const lB = LB + wave * 512;
    const size_t rowblk = (size_t)64 * (size_t)K;         // 64 rows, in elems

#define STG_A(db, hf, T) do {                                               \
    const bf16* g_ = gA + (size_t)((hf) * 2) * rowblk + (size_t)(T) * 64;   \
    async_ld16(g_,          lA + ((db) * 2 + (hf)) * 8192);                 \
    async_ld16(g_ + rowblk, lA + ((db) * 2 + (hf)) * 8192 + 4096);          \
} while (0)
#define STG_B(db, hf, T) do {                                               \
    const bf16* g_ = gB + (size_t)((hf) * 2) * rowblk + (size_t)(T) * 64;   \
    async_ld16(g_,          lB + ((db) * 2 + (hf)) * 8192);                 \
    async_ld16(g_ + rowblk, lB + ((db) * 2 + (hf)) * 8192 + 4096);          \
} while (0)

    // ---- fragment read addresses (swizzled): phys chunk = (ks*4+fg) ^ (row&7)
    const int fr    = lane & 15;
    const int fg    = lane >> 4;                          // 0..3
    const int pc0   = ((fg)     ^ (fr & 7)) * 8;          // elem offset, ks=0
    const int pc1   = ((4 + fg) ^ (fr & 7)) * 8;          // ks=1
    const int raOff = wm * 8192 + fr * 64;                // own A-half base + row
    const int rbOff = (wn >> 1) * 8192 + ((wn & 1) * 64 + fr) * 64;

    f32x4  acc[2][2][4][2] = {};   // [qm][qn][mi][ni] -> 128 regs
    bf16x8 af[4][2];               // A frags, current qm (32 VGPR)
    bf16x8 bg[2][2][2];            // B frags [qn][ni][ks], live all tile (32 VGPR)

#define LDF_A(db, qm) do { _Pragma("unroll")                                  \
    for (int mi_ = 0; mi_ < 4; ++mi_) {                                       \
        const bf16* p_ = LA + (db) * 16384 + raOff + ((qm) * 64 + mi_ * 16) * 64; \
        af[mi_][0] = *(const bf16x8*)(p_ + pc0);                              \
        af[mi_][1] = *(const bf16x8*)(p_ + pc1); } } while (0)
#define LDF_B(db, qn) do { _Pragma("unroll")                                  \
    for (int ni_ = 0; ni_ < 2; ++ni_) {                                       \
        const bf16* p_ = LB + (db) * 16384 + rbOff + ((qn) * 32 + ni_ * 16) * 64; \
        bg[qn][ni_][0] = *(const bf16x8*)(p_ + pc0);                          \
        bg[qn][ni_][1] = *(const bf16x8*)(p_ + pc1); } } while (0)
#define MFMAQ(qm, qn) do {                                                    \
    _Pragma("unroll") for (int mi_ = 0; mi_ < 4; ++mi_)                       \
    _Pragma("unroll") for (int ni_ = 0; ni_ < 2; ++ni_) {                     \
        acc[qm][qn][mi_][ni_] = mfma16(af[mi_][0], bg[qn][ni_][0], acc[qm][qn][mi_][ni_]); \
        acc[qm][qn][mi_][ni_] = mfma16(af[mi_][1], bg[qn][ni_][1], acc[qm][qn][mi_][ni_]); } \
} while (0)
#define VM0   asm volatile("s_waitcnt vmcnt(0)" ::: "memory")
#define BAR   __builtin_amdgcn_s_barrier()
#define PRIO1 __builtin_amdgcn_s_setprio(1)
#define PRIO0 __builtin_amdgcn_s_setprio(0)

// one K-tile: bufc = current data, bufo = stage target for tile Tnx
#define KTILE(bufc, bufo, Tnx) do {                                           \
    VM0; BAR;                                                                 \
    STG_B(bufo, 0, Tnx); STG_B(bufo, 1, Tnx);                                 \
    LDF_B(bufc, 0); LDF_B(bufc, 1); LDF_A(bufc, 0);                           \
    PRIO1; MFMAQ(0, 0); MFMAQ(0, 1); PRIO0;                                   \
    STG_A(bufo, 0, Tnx); STG_A(bufo, 1, Tnx);                                 \
    LDF_A(bufc, 1);                                                           \
    PRIO1; MFMAQ(1, 0); MFMAQ(1, 1); PRIO0;                                   \
} while (0)

    // ---- prologue: stage tile 0 into buf0 (8 loads)
    STG_B(0, 0, 0); STG_B(0, 1, 0); STG_A(0, 0, 0); STG_A(0, 1, 0);

    for (int kt = 0; kt < NT; kt += 2) {
        const int Tp1 = kt + 1;                            // always < NT
        const int Tp2 = (kt + 2 < NT) ? kt + 2 : NT - 1;   // clamp: dead-slot rewrite
        KTILE(0, 1, Tp1);
        KTILE(1, 0, Tp2);
    }

    // ---- epilogue: C/D layout col=lane&15, row=(lane>>4)*4+reg [m89-verified]
    const int col  = lane & 15;
    const int row4 = (lane >> 4) * 4;
    const size_t cOff = (size_t)z * cB;
    #pragma unroll
    for (int qm = 0; qm < 2; ++qm)
    #pragma unroll
    for (int mi = 0; mi < 4; ++mi) {
        const int mBase = m0 + wm * 128 + qm * 64 + mi * 16 + row4;
        #pragma unroll
        for (int qn = 0; qn < 2; ++qn)
        #pragma unroll
        for (int ni = 0; ni < 2; ++ni) {
            const int n = n0 + wn * 64 + qn * 32 + ni * 16 + col;
            const float bcol = (BIASMODE == 1) ? bias[n] : 0.0f;
            #pragma unroll
            for (int r = 0; r < 4; ++r) {
                const int m = mBase + r;
                float v = acc[qm][qn][mi][ni][r];
                if (BIASMODE == 1) v += bcol;
                if (BIASMODE == 2) v += bias[m];
                if (SCORE) { v *= scale; if (n > m) v = -1e30f; }
                if (GELU)  { v = 0.5f * v * (1.0f + erff(v * 0.70710678118654752f)); }
                const size_t idx = cOff + (size_t)m * (size_t)N + (size_t)n;
                if (RESID) v += resid[idx];
                if (OUTF32) ((float*)Cv)[idx] = v;
                else        ((bf16*)Cv)[idx]  = (bf16)v;
            }
        }
    }
#undef STG_A
#undef STG_B
#undef LDF_A
#undef LDF_B
#undef MFMAQ
#undef VM0
#undef BAR
#undef PRIO1
#undef PRIO0
#undef KTILE
}

// ---------------- RMSNorm: fp32 row(1024) -> bf16 ----------------
__global__ __launch_bounds__(256) void rmsnorm_kernel(
    const float* __restrict__ x, const float* __restrict__ w, bf16* __restrict__ out)
{
    const int row = blockIdx.x;
    const int t   = threadIdx.x;
    const float4 v = ((const float4*)(x + (size_t)row * DIM))[t];
    float ss = v.x * v.x + v.y * v.y + v.z * v.z + v.w * v.w;
    #pragma unroll
    for (int off = 32; off; off >>= 1) ss += __shfl_down(ss, off);
    __shared__ float part[4];
    if ((t & 63) == 0) part[t >> 6] = ss;
    __syncthreads();
    const float tot  = part[0] + part[1] + part[2] + part[3];
    const float rinv = rsqrtf(tot * (1.0f / DIM) + 1e-6f);
    const float4 wv = ((const float4*)w)[t];
    bf16x4 o;
    o[0] = (bf16)(v.x * rinv * wv.x);
    o[1] = (bf16)(v.y * rinv * wv.y);
    o[2] = (bf16)(v.z * rinv * wv.z);
    o[3] = (bf16)(v.w * rinv * wv.w);
    *(bf16x4*)(out + (size_t)row * DIM + t * 4) = o;
}

// ---------------- weight fp32 [R,C] -> bf16 transposed [C,R] ----------------
__global__ __launch_bounds__(256) void transpose_w_kernel(
    const float* __restrict__ src, bf16* __restrict__ dst, int R, int C)
{
    __shared__ float tile[32][33];
    const int tx = threadIdx.x & 31;
    const int ty = threadIdx.x >> 5;     // 0..7
    const int c0 = blockIdx.x * 32;
    const int r0 = blockIdx.y * 32;
    #pragma unroll
    for (int j = 0; j < 32; j += 8)
        tile[ty + j][tx] = src[(size_t)(r0 + ty + j) * C + c0 + tx];
    __syncthreads();
    #pragma unroll
    for (int j = 0; j < 32; j += 8)
        dst[(size_t)(c0 + ty + j) * R + r0 + tx] = (bf16)tile[tx][ty + j];
}

// ---------------- causal softmax over S rows, in place (bf16) ----------------
// Writes out to the 256-aligned extent so the 256-tile causal PV (kEnd=m0+256)
// only ever reads normalized values (masked entries become exp(-huge)=0).
__global__ __launch_bounds__(256) void softmax_kernel(bf16* __restrict__ S)
{
    const int t = blockIdx.x;
    const int b = blockIdx.y;
    bf16* p = S + ((size_t)b * SEQ + t) * SEQ;
    const int send = ((t >> 8) + 1) << 8;
    const int tid  = threadIdx.x;
    const int lane = tid & 63;
    const int wave = tid >> 6;

    float v[8];
    int cnt = 0;
    float m = -3.0e38f;
    for (int i = tid; i < send; i += 256) { const float f = (float)p[i]; v[cnt++] = f; m = fmaxf(m, f); }
    #pragma unroll
    for (int off = 32; off; off >>= 1) m = fmaxf(m, __shfl_down(m, off));
    __shared__ float red[4];
    if (lane == 0) red[wave] = m;
    __syncthreads();
    m = fmaxf(fmaxf(red[0], red[1]), fmaxf(red[2], red[3]));
    __syncthreads();

    float s = 0.0f;
    for (int k2 = 0; k2 < cnt; ++k2) { v[k2] = __expf(v[k2] - m); s += v[k2]; }
    #pragma unroll
    for (int off = 32; off; off >>= 1) s += __shfl_down(s, off);
    if (lane == 0) red[wave] = s;
    __syncthreads();
    s = red[0] + red[1] + red[2] + red[3];
    const float inv = 1.0f / s;
    cnt = 0;
    for (int i = tid; i < send; i += 256) p[i] = (bf16)(v[cnt++] * inv);
}

extern "C" void kernel_launch(void* const* d_in, const int* in_sizes, int n_in,
                              void* d_out, int out_size, void* d_ws, size_t ws_size,
                              hipStream_t stream)
{
    const float* x   = (const float*)d_in[0];
    const float* anw = (const float*)d_in[1];
    const float* mnw = (const float*)d_in[2];
    const float* wq  = (const float*)d_in[3];
    const float* bq  = (const float*)d_in[4];
    const float* wk  = (const float*)d_in[5];
    const float* bk  = (const float*)d_in[6];
    const float* wv  = (const float*)d_in[7];
    const float* bv  = (const float*)d_in[8];
    const float* wo  = (const float*)d_in[9];
    const float* bo  = (const float*)d_in[10];
    const float* w1  = (const float*)d_in[11];
    const float* b1  = (const float*)d_in[12];
    const float* w2  = (const float*)d_in[13];
    const float* b2  = (const float*)d_in[14];
    float* out = (float*)d_out;

    char* ws = (char*)d_ws;
    const size_t MB = 1024 * 1024;
    bf16* wqT = (bf16*)(ws + 0 * MB);    // 1024x1024  (2 MB)
    bf16* wkT = (bf16*)(ws + 2 * MB);
    bf16* wvT = (bf16*)(ws + 4 * MB);
    bf16* woT = (bf16*)(ws + 6 * MB);
    bf16* w1T = (bf16*)(ws + 8 * MB);    // 4096x1024  (8 MB)
    bf16* w2T = (bf16*)(ws + 16 * MB);   // 1024x4096  (8 MB)
    bf16* xn  = (bf16*)(ws + 24 * MB);   // 16384x1024 (32 MB)
    bf16* q   = (bf16*)(ws + 56 * MB);   // 32 MB
    bf16* k   = (bf16*)(ws + 88 * MB);   // 32 MB
    bf16* vT  = (bf16*)(ws + 120 * MB);  // 8 x 1024 x 2048 (32 MB)
    bf16* S   = (bf16*)(ws + 152 * MB);  // 8 x 2048 x 2048 (64 MB) -> end 216 MB
    bf16* attn = xn;                     // alias: xn dead after vT GEMM
    bf16* h    = q;                      // alias: q dead after score GEMM
    bf16* mid  = k;                      // alias: spans k+vT+S (128 MB), all dead after PV

    const dim3 blk(256);
    const dim3 blkG(512);

    // weights fp32 -> bf16, transposed to [N,K]
    transpose_w_kernel<<<dim3(DIM / 32, DIM / 32), blk, 0, stream>>>(wq, wqT, DIM, DIM);
    transpose_w_kernel<<<dim3(DIM / 32, DIM / 32), blk, 0, stream>>>(wk, wkT, DIM, DIM);
    transpose_w_kernel<<<dim3(DIM / 32, DIM / 32), blk, 0, stream>>>(wv, wvT, DIM, DIM);
    transpose_w_kernel<<<dim3(DIM / 32, DIM / 32), blk, 0, stream>>>(wo, woT, DIM, DIM);
    transpose_w_kernel<<<dim3(HID / 32, DIM / 32), blk, 0, stream>>>(w1, w1T, DIM, HID);
    transpose_w_kernel<<<dim3(DIM / 32, HID / 32), blk, 0, stream>>>(w2, w2T, HID, DIM);

    // xn = rmsnorm(x, attn_norm_w)
    rmsnorm_kernel<<<NROWS, blk, 0, stream>>>(x, anw, xn);

    // q = xn @ wq + bq ; k = xn @ wk + bk
    gemm256_kernel<0, 1, 0, 0, 0, 0><<<dim3(DIM / 256, NROWS / 256, 1), blkG, 0, stream>>>(
        xn, 0, wqT, 0, q, 0, bq, nullptr, NROWS, DIM, DIM, 1.0f);
    gemm256_kernel<0, 1, 0, 0, 0, 0><<<dim3(DIM / 256, NROWS / 256, 1), blkG, 0, stream>>>(
        xn, 0, wkT, 0, k, 0, bk, nullptr, NROWS, DIM, DIM, 1.0f);
    // vT[b][d][t] = (wv^T @ xn[b]^T)[d][t] + bv[d]  (bias per row)
    gemm256_kernel<0, 2, 0, 0, 0, 0><<<dim3(SEQ / 256, DIM / 256, BATCH), blkG, 0, stream>>>(
        wvT, 0, xn, (size_t)SEQ * DIM, vT, (size_t)DIM * SEQ, bv, nullptr, DIM, SEQ, DIM, 1.0f);

    // S[b] = q[b] @ k[b]^T / 32, causal mask, skip upper tiles
    gemm256_kernel<0, 0, 0, 0, 1, 0><<<dim3(SEQ / 256, SEQ / 256, BATCH), blkG, 0, stream>>>(
        q, (size_t)SEQ * DIM, k, (size_t)SEQ * DIM, S, (size_t)SEQ * SEQ,
        nullptr, nullptr, SEQ, SEQ, DIM, 0.03125f);

    // softmax rows in place
    softmax_kernel<<<dim3(SEQ, BATCH), blk, 0, stream>>>(S);

    // attn[b] = P[b] @ V[b]  (A=S, Bt=vT, causal K-stop)
    gemm256_kernel<0, 0, 0, 0, 0, 1><<<dim3(DIM / 256, SEQ / 256, BATCH), blkG, 0, stream>>>(
        S, (size_t)SEQ * SEQ, vT, (size_t)DIM * SEQ, attn, (size_t)SEQ * DIM,
        nullptr, nullptr, SEQ, DIM, SEQ, 1.0f);

    // x1 = x + attn @ wo + bo  -> d_out (fp32)
    gemm256_kernel<1, 1, 1, 0, 0, 0><<<dim3(DIM / 256, NROWS / 256, 1), blkG, 0, stream>>>(
        attn, 0, woT, 0, out, 0, bo, x, NROWS, DIM, DIM, 1.0f);

    // h = rmsnorm(x1, mlp_norm_w)
    rmsnorm_kernel<<<NROWS, blk, 0, stream>>>(out, mnw, h);

    // mid = gelu(h @ w1 + b1)
    gemm256_kernel<0, 1, 0, 1, 0, 0><<<dim3(HID / 256, NROWS / 256, 1), blkG, 0, stream>>>(
        h, 0, w1T, 0, mid, 0, b1, nullptr, NROWS, HID, DIM, 1.0f);

    // out = x1 + mid @ w2 + b2  (fp32)
    gemm256_kernel<1, 1, 1, 0, 0, 0><<<dim3(DIM / 256, NROWS / 256, 1), blkG, 0, stream>>>(
        mid, 0, w2T, 0, out, 0, b2, out, NROWS, DIM, HID, 1.0f);
}

// Round 6
// 810.871 us; speedup vs baseline: 1.1669x; 1.1669x over previous
//
#include <hip/hip_runtime.h>
#include <hip/hip_bf16.h>

typedef __bf16 bf16;
typedef __bf16 bf16x8 __attribute__((ext_vector_type(8)));
typedef __bf16 bf16x4 __attribute__((ext_vector_type(4)));
typedef float  f32x4  __attribute__((ext_vector_type(4)));

#define DIM   1024
#define SEQ   2048
#define BATCH 8
#define NROWS (BATCH * SEQ)
#define HID   4096

// ---------------- async global->LDS (16B/lane) ----------------
__device__ __forceinline__ void async_ld16(const bf16* g, bf16* l) {
    __builtin_amdgcn_global_load_lds(
        (__attribute__((address_space(1))) void*)(g),
        (__attribute__((address_space(3))) void*)(l),
        16, 0, 0);
}

__device__ __forceinline__ f32x4 mfma16(bf16x8 a, bf16x8 b, f32x4 c) {
    return __builtin_amdgcn_mfma_f32_16x16x32_bf16(a, b, c, 0, 0, 0);
}

// =====================================================================
// 256x256-tile, BK=64, 512-thread (8-wave) pipelined GEMM (v6).
//   C[M,N] = A[M,K] @ Bt[N,K]^T  (+epilogue variants)
// K-loop body = v3 exactly (best measured of 5 schedule variants;
// rounds 1-5 showed the K-loop schedule is NOT the binding constraint:
// all variants 195-267us, MfmaUtil 22-30%).
//
// v6 deltas (outside the K-loop):
//  - NO XCD swizzle. For panel-shaped GEMMs (e.g. w1: 64 m-rows x 16
//    n-cols) the swizzle gave each XCD whole m-rows -> the full 8MB
//    B-panel thrashed its 4MB L2 and re-streamed from HBM (w1 FETCH
//    148MB vs 40MB inputs). Default round-robin gives each XCD ~2
//    n-cols -> ~1MB L2-resident B slice. [probe: FETCH_SIZE]
//  - lda/ldb row strides + bias2 (BIASMODE 3: bias[n<1024]=b1, else b2)
//    to support the fused q|k GEMM over stacked [wqT;wkT].
// BIASMODE: 0 none, 1 bias[n], 2 bias[m], 3 split bias[n] (bias/bias2);
// SCORE: scale+causal, skip fully-masked tiles; PV: causal K-stop.
// =====================================================================
template<int OUTF32, int BIASMODE, int RESID, int GELU, int SCORE, int PV>
__global__ __launch_bounds__(512, 2) void gemm256_kernel(
    const bf16* __restrict__ A, size_t aB, int lda,
    const bf16* __restrict__ B, size_t bB, int ldb,
    void* __restrict__ Cv, size_t cB,
    const float* __restrict__ bias,
    const float* __restrict__ bias2,
    const float* __restrict__ resid,
    int M, int N, int K, float scale)
{
    __shared__ alignas(16) bf16 LA[2 * 2 * 8192];   // [db][half][128*64]
    __shared__ alignas(16) bf16 LB[2 * 2 * 8192];

    const int m0 = blockIdx.y * 256;
    const int n0 = blockIdx.x * 256;
    if (SCORE && n0 >= m0 + 256) return;   // fully-masked tile

    const int z = blockIdx.z;
    A += (size_t)z * aB;
    B += (size_t)z * bB;

    const int t    = threadIdx.x;
    const int lane = t & 63;
    const int wave = t >> 6;        // 0..7
    const int wr   = wave >> 2;     // 0..1  (64-row band within quadrant)
    const int wc   = wave & 3;      // 0..3  (32-col band within quadrant)

    const int kEnd = PV ? (m0 + 256) : K;
    const int NT   = kEnd >> 6;     // K-tiles of 64; always even, >= 4 here

    // ---- staging addresses: thread t covers flat 16B-chunk of a half
    const int srow = t >> 3;                              // 0..63
    const int sd   = ((t & 7) ^ (srow & 7)) * 8;          // inverse-swizzled data col
    const bf16* gA = A + (size_t)(m0 + srow) * (size_t)lda + sd;
    const bf16* gB = B + (size_t)(n0 + srow) * (size_t)ldb + sd;
    bf16* const lA = LA + wave * 512;                     // + lane*16B by HW
    bf16* const lB = LB + wave * 512;
    const size_t rowA = (size_t)64 * (size_t)lda;         // 64 rows, in elems
    const size_t rowB = (size_t)64 * (size_t)ldb;

#define STG_A(db, hf, T) do {                                               \
    const bf16* g_ = gA + (size_t)((hf) * 2) * rowA + (size_t)(T) * 64;     \
    async_ld16(g_,        lA + ((db) * 2 + (hf)) * 8192);                   \
    async_ld16(g_ + rowA, lA + ((db) * 2 + (hf)) * 8192 + 4096);            \
} while (0)
#define STG_B(db, hf, T) do {                                               \
    const bf16* g_ = gB + (size_t)((hf) * 2) * rowB + (size_t)(T) * 64;     \
    async_ld16(g_,        lB + ((db) * 2 + (hf)) * 8192);                   \
    async_ld16(g_ + rowB, lB + ((db) * 2 + (hf)) * 8192 + 4096);            \
} while (0)

    // ---- fragment read addresses (swizzled): phys chunk = (ks*4+fg) ^ (row&7)
    const int fr    = lane & 15;
    const int fg    = lane >> 4;                          // 0..3
    const int pc0   = ((fg)     ^ (fr & 7)) * 8;          // elem offset, ks=0
    const int pc1   = ((4 + fg) ^ (fr & 7)) * 8;          // ks=1
    const int raOff = (wr * 64 + fr) * 64;                // row-in-half * 64
    const int rbOff = (wc * 32 + fr) * 64;

    f32x4  acc[2][2][4][2] = {};   // [qm][qn][mi][ni]
    bf16x8 af[4][2];               // A frags for the current half
    bf16x8 bg[2][2][2];            // B frags, BOTH halves live

#define LDF_A(db, hf) do { _Pragma("unroll")                                  \
    for (int mi_ = 0; mi_ < 4; ++mi_) {                                       \
        const bf16* p_ = LA + ((db) * 2 + (hf)) * 8192 + raOff + mi_ * 1024;  \
        af[mi_][0] = *(const bf16x8*)(p_ + pc0);                              \
        af[mi_][1] = *(const bf16x8*)(p_ + pc1); } } while (0)
#define LDF_B(db, hf) do { _Pragma("unroll")                                  \
    for (int ni_ = 0; ni_ < 2; ++ni_) {                                       \
        const bf16* p_ = LB + ((db) * 2 + (hf)) * 8192 + rbOff + ni_ * 1024;  \
        bg[hf][ni_][0] = *(const bf16x8*)(p_ + pc0);                          \
        bg[hf][ni_][1] = *(const bf16x8*)(p_ + pc1); } } while (0)
#define MFMAQ(qm, qn) do {                                                    \
    __builtin_amdgcn_s_setprio(1);                                            \
    _Pragma("unroll") for (int mi_ = 0; mi_ < 4; ++mi_)                       \
    _Pragma("unroll") for (int ni_ = 0; ni_ < 2; ++ni_) {                     \
        acc[qm][qn][mi_][ni_] = mfma16(af[mi_][0], bg[qn][ni_][0], acc[qm][qn][mi_][ni_]); \
        acc[qm][qn][mi_][ni_] = mfma16(af[mi_][1], bg[qn][ni_][1], acc[qm][qn][mi_][ni_]); } \
    __builtin_amdgcn_s_setprio(0);                                            \
} while (0)
#define LGKM0 do { asm volatile("s_waitcnt lgkmcnt(0)" ::: "memory");         \
                   __builtin_amdgcn_sched_barrier(0); } while (0)
#define VM6   asm volatile("s_waitcnt vmcnt(6)" ::: "memory")
#define VM8   asm volatile("s_waitcnt vmcnt(8)" ::: "memory")
#define BAR   __builtin_amdgcn_s_barrier()

    // ---- prologue: stage tiles 0 and 1 entirely (16 loads, in the
    // steady-state slot order); retire tile 0 (first 8); pre-read frags.
    STG_A(0, 0, 0); STG_B(0, 0, 0); STG_B(0, 1, 0); STG_A(0, 1, 0);
    STG_A(1, 0, 1); STG_B(1, 0, 1); STG_B(1, 1, 1); STG_A(1, 1, 1);
    VM8;                                  // tile0 retired; tile1's 8 in flight
    BAR;
    LDF_A(0, 0); LDF_B(0, 0); LDF_B(0, 1);

    for (int kt = 0; kt < NT; kt += 2) {
        const int Tp2 = (kt + 2 < NT) ? kt + 2 : NT - 1;   // clamp keeps counts exact
        const int Tp3 = (kt + 3 < NT) ? kt + 3 : NT - 1;

        // ---- PA(kt), buf0: MFMA q(0,0),(0,1) ----
        LGKM0;
        STG_A(0, 0, Tp2); STG_B(0, 0, Tp2);  // tile kt+2 -> buf0 (slots freed)
        MFMAQ(0, 0); MFMAQ(0, 1);
        LDF_A(0, 1);                         // af <- buf0.A1 (this tile)
        VM6; BAR;                            // retires (kt+1).A0,B0,B1

        // ---- PB(kt): MFMA q(1,0),(1,1); prefetch tile kt+1 frags ----
        LGKM0;
        STG_B(0, 1, Tp2); STG_A(0, 1, Tp2);  // tile kt+2 -> buf0
        MFMAQ(1, 0);
        LDF_B(1, 0);                         // bg0 <- buf1.B0 (tile kt+1)
        MFMAQ(1, 1);
        LDF_B(1, 1);                         // bg1 <- buf1.B1
        LDF_A(1, 0);                         // af  <- buf1.A0
        VM8; BAR;                            // retires (kt+1).A1

        // ---- PA(kt+1), buf1 ----
        LGKM0;
        STG_A(1, 0, Tp3); STG_B(1, 0, Tp3);  // tile kt+3 -> buf1
        MFMAQ(0, 0); MFMAQ(0, 1);
        LDF_A(1, 1);                         // af <- buf1.A1
        VM6; BAR;                            // retires (kt+2).A0,B0,B1

        // ---- PB(kt+1): prefetch tile kt+2 frags ----
        LGKM0;
        STG_B(1, 1, Tp3); STG_A(1, 1, Tp3);  // tile kt+3 -> buf1
        MFMAQ(1, 0);
        LDF_B(0, 0);                         // bg0 <- buf0.B0 (tile kt+2)
        MFMAQ(1, 1);
        LDF_B(0, 1);                         // bg1 <- buf0.B1
        LDF_A(0, 0);                         // af  <- buf0.A0
        VM8; BAR;                            // retires (kt+2).A1
    }

    // ---- epilogue: C/D layout col=lane&15, row=(lane>>4)*4+reg [m89-verified]
    const int col  = lane & 15;
    const int row4 = (lane >> 4) * 4;
    const size_t cOff = (size_t)z * cB;
    #pragma unroll
    for (int qm = 0; qm < 2; ++qm)
    #pragma unroll
    for (int mi = 0; mi < 4; ++mi) {
        const int mBase = m0 + qm * 128 + wr * 64 + mi * 16 + row4;
        #pragma unroll
        for (int qn = 0; qn < 2; ++qn)
        #pragma unroll
        for (int ni = 0; ni < 2; ++ni) {
            const int n = n0 + qn * 128 + wc * 32 + ni * 16 + col;
            float bcol = 0.0f;
            if (BIASMODE == 1) bcol = bias[n];
            if (BIASMODE == 3) bcol = (n < 1024) ? bias[n] : bias2[n - 1024];
            #pragma unroll
            for (int r = 0; r < 4; ++r) {
                const int m = mBase + r;
                float v = acc[qm][qn][mi][ni][r];
                if (BIASMODE == 1 || BIASMODE == 3) v += bcol;
                if (BIASMODE == 2) v += bias[m];
                if (SCORE) { v *= scale; if (n > m) v = -1e30f; }
                if (GELU)  { v = 0.5f * v * (1.0f + erff(v * 0.70710678118654752f)); }
                const size_t idx = cOff + (size_t)m * (size_t)N + (size_t)n;
                if (RESID) v += resid[idx];
                if (OUTF32) ((float*)Cv)[idx] = v;
                else        ((bf16*)Cv)[idx]  = (bf16)v;
            }
        }
    }
#undef STG_A
#undef STG_B
#undef LDF_A
#undef LDF_B
#undef MFMAQ
#undef LGKM0
#undef VM6
#undef VM8
#undef BAR
}

// ---------------- RMSNorm: fp32 row(1024) -> bf16 ----------------
__global__ __launch_bounds__(256) void rmsnorm_kernel(
    const float* __restrict__ x, const float* __restrict__ w, bf16* __restrict__ out)
{
    const int row = blockIdx.x;
    const int t   = threadIdx.x;
    const float4 v = ((const float4*)(x + (size_t)row * DIM))[t];
    float ss = v.x * v.x + v.y * v.y + v.z * v.z + v.w * v.w;
    #pragma unroll
    for (int off = 32; off; off >>= 1) ss += __shfl_down(ss, off);
    __shared__ float part[4];
    if ((t & 63) == 0) part[t >> 6] = ss;
    __syncthreads();
    const float tot  = part[0] + part[1] + part[2] + part[3];
    const float rinv = rsqrtf(tot * (1.0f / DIM) + 1e-6f);
    const float4 wv = ((const float4*)w)[t];
    bf16x4 o;
    o[0] = (bf16)(v.x * rinv * wv.x);
    o[1] = (bf16)(v.y * rinv * wv.y);
    o[2] = (bf16)(v.z * rinv * wv.z);
    o[3] = (bf16)(v.w * rinv * wv.w);
    *(bf16x4*)(out + (size_t)row * DIM + t * 4) = o;
}

// ---------------- weight fp32 [R,C] -> bf16 transposed [C,R] ----------------
__global__ __launch_bounds__(256) void transpose_w_kernel(
    const float* __restrict__ src, bf16* __restrict__ dst, int R, int C)
{
    __shared__ float tile[32][33];
    const int tx = threadIdx.x & 31;
    const int ty = threadIdx.x >> 5;     // 0..7
    const int c0 = blockIdx.x * 32;
    const int r0 = blockIdx.y * 32;
    #pragma unroll
    for (int j = 0; j < 32; j += 8)
        tile[ty + j][tx] = src[(size_t)(r0 + ty + j) * C + c0 + tx];
    __syncthreads();
    #pragma unroll
    for (int j = 0; j < 32; j += 8)
        dst[(size_t)(c0 + ty + j) * R + r0 + tx] = (bf16)tile[tx][ty + j];
}

// ---------------- causal softmax over S rows, in place (bf16) ----------------
// Writes out to the 256-aligned extent so the 256-tile causal PV (kEnd=m0+256)
// only ever reads normalized values (masked entries become exp(-huge)=0).
__global__ __launch_bounds__(256) void softmax_kernel(bf16* __restrict__ S)
{
    const int t = blockIdx.x;
    const int b = blockIdx.y;
    bf16* p = S + ((size_t)b * SEQ + t) * SEQ;
    const int send = ((t >> 8) + 1) << 8;
    const int tid  = threadIdx.x;
    const int lane = tid & 63;
    const int wave = tid >> 6;

    float v[8];
    int cnt = 0;
    float m = -3.0e38f;
    for (int i = tid; i < send; i += 256) { const float f = (float)p[i]; v[cnt++] = f; m = fmaxf(m, f); }
    #pragma unroll
    for (int off = 32; off; off >>= 1) m = fmaxf(m, __shfl_down(m, off));
    __shared__ float red[4];
    if (lane == 0) red[wave] = m;
    __syncthreads();
    m = fmaxf(fmaxf(red[0], red[1]), fmaxf(red[2], red[3]));
    __syncthreads();

    float s = 0.0f;
    for (int k2 = 0; k2 < cnt; ++k2) { v[k2] = __expf(v[k2] - m); s += v[k2]; }
    #pragma unroll
    for (int off = 32; off; off >>= 1) s += __shfl_down(s, off);
    if (lane == 0) red[wave] = s;
    __syncthreads();
    s = red[0] + red[1] + red[2] + red[3];
    const float inv = 1.0f / s;
    cnt = 0;
    for (int i = tid; i < send; i += 256) p[i] = (bf16)(v[cnt++] * inv);
}

extern "C" void kernel_launch(void* const* d_in, const int* in_sizes, int n_in,
                              void* d_out, int out_size, void* d_ws, size_t ws_size,
                              hipStream_t stream)
{
    const float* x   = (const float*)d_in[0];
    const float* anw = (const float*)d_in[1];
    const float* mnw = (const float*)d_in[2];
    const float* wq  = (const float*)d_in[3];
    const float* bq  = (const float*)d_in[4];
    const float* wk  = (const float*)d_in[5];
    const float* bk  = (const float*)d_in[6];
    const float* wv  = (const float*)d_in[7];
    const float* bv  = (const float*)d_in[8];
    const float* wo  = (const float*)d_in[9];
    const float* bo  = (const float*)d_in[10];
    const float* w1  = (const float*)d_in[11];
    const float* b1  = (const float*)d_in[12];
    const float* w2  = (const float*)d_in[13];
    const float* b2  = (const float*)d_in[14];
    float* out = (float*)d_out;

    char* ws = (char*)d_ws;
    const size_t MB = 1024 * 1024;
    bf16* wqT = (bf16*)(ws + 0 * MB);    // 1024x1024 (2 MB); wq|wk stacked = [2048,1024]
    bf16* wkT = (bf16*)(ws + 2 * MB);
    bf16* wvT = (bf16*)(ws + 4 * MB);
    bf16* woT = (bf16*)(ws + 6 * MB);
    bf16* w1T = (bf16*)(ws + 8 * MB);    // 4096x1024  (8 MB)
    bf16* w2T = (bf16*)(ws + 16 * MB);   // 1024x4096  (8 MB)
    bf16* xn  = (bf16*)(ws + 24 * MB);   // 16384x1024 (32 MB)
    bf16* qk  = (bf16*)(ws + 56 * MB);   // 16384x2048 (64 MB): per row q|k
    bf16* vT  = (bf16*)(ws + 120 * MB);  // 8 x 1024 x 2048 (32 MB)
    bf16* S   = (bf16*)(ws + 152 * MB);  // 8 x 2048 x 2048 (64 MB) -> end 216 MB
    bf16* attn = xn;                     // alias: xn dead after vT GEMM
    bf16* h    = qk;                     // alias: qk dead after score GEMM (32 MB used)
    bf16* mid  = (bf16*)(ws + 88 * MB);  // alias: spans qk-2nd-half + vT + S (128 MB)

    const dim3 blk(256);
    const dim3 blkG(512);

    // weights fp32 -> bf16, transposed to [N,K]
    transpose_w_kernel<<<dim3(DIM / 32, DIM / 32), blk, 0, stream>>>(wq, wqT, DIM, DIM);
    transpose_w_kernel<<<dim3(DIM / 32, DIM / 32), blk, 0, stream>>>(wk, wkT, DIM, DIM);
    transpose_w_kernel<<<dim3(DIM / 32, DIM / 32), blk, 0, stream>>>(wv, wvT, DIM, DIM);
    transpose_w_kernel<<<dim3(DIM / 32, DIM / 32), blk, 0, stream>>>(wo, woT, DIM, DIM);
    transpose_w_kernel<<<dim3(HID / 32, DIM / 32), blk, 0, stream>>>(w1, w1T, DIM, HID);
    transpose_w_kernel<<<dim3(DIM / 32, HID / 32), blk, 0, stream>>>(w2, w2T, HID, DIM);

    // xn = rmsnorm(x, attn_norm_w)
    rmsnorm_kernel<<<NROWS, blk, 0, stream>>>(x, anw, xn);

    // qk = xn @ [wq|wk] + [bq|bk]   (fused: one pass over xn)
    gemm256_kernel<0, 3, 0, 0, 0, 0><<<dim3(2048 / 256, NROWS / 256, 1), blkG, 0, stream>>>(
        xn, 0, DIM, wqT, 0, DIM, qk, 0, bq, bk, nullptr, NROWS, 2048, DIM, 1.0f);

    // vT[b][d][t] = (wv^T @ xn[b]^T)[d][t] + bv[d]  (bias per row)
    gemm256_kernel<0, 2, 0, 0, 0, 0><<<dim3(SEQ / 256, DIM / 256, BATCH), blkG, 0, stream>>>(
        wvT, 0, DIM, xn, (size_t)SEQ * DIM, DIM, vT, (size_t)DIM * SEQ,
        bv, nullptr, nullptr, DIM, SEQ, DIM, 1.0f);

    // S[b] = q[b] @ k[b]^T / 32, causal mask, skip upper tiles
    // q rows: qk + row*2048, k rows: qk + row*2048 + 1024 (lda=ldb=2048)
    gemm256_kernel<0, 0, 0, 0, 1, 0><<<dim3(SEQ / 256, SEQ / 256, BATCH), blkG, 0, stream>>>(
        qk, (size_t)SEQ * 2048, 2048, qk + 1024, (size_t)SEQ * 2048, 2048,
        S, (size_t)SEQ * SEQ, nullptr, nullptr, nullptr, SEQ, SEQ, DIM, 0.03125f);

    // softmax rows in place
    softmax_kernel<<<dim3(SEQ, BATCH), blk, 0, stream>>>(S);

    // attn[b] = P[b] @ V[b]  (A=S, Bt=vT, causal K-stop)
    gemm256_kernel<0, 0, 0, 0, 0, 1><<<dim3(DIM / 256, SEQ / 256, BATCH), blkG, 0, stream>>>(
        S, (size_t)SEQ * SEQ, SEQ, vT, (size_t)DIM * SEQ, SEQ,
        attn, (size_t)SEQ * DIM, nullptr, nullptr, nullptr, SEQ, DIM, SEQ, 1.0f);

    // x1 = x + attn @ wo + bo  -> d_out (fp32)
    gemm256_kernel<1, 1, 1, 0, 0, 0><<<dim3(DIM / 256, NROWS / 256, 1), blkG, 0, stream>>>(
        attn, 0, DIM, woT, 0, DIM, out, 0, bo, nullptr, x, NROWS, DIM, DIM, 1.0f);

    // h = rmsnorm(x1, mlp_norm_w)
    rmsnorm_kernel<<<NROWS, blk, 0, stream>>>(out, mnw, h);

    // mid = gelu(h @ w1 + b1)
    gemm256_kernel<0, 1, 0, 1, 0, 0><<<dim3(HID / 256, NROWS / 256, 1), blkG, 0, stream>>>(
        h, 0, DIM, w1T, 0, DIM, mid, 0, b1, nullptr, nullptr, NROWS, HID, DIM, 1.0f);

    // out = x1 + mid @ w2 + b2  (fp32)
    gemm256_kernel<1, 1, 1, 0, 0, 0><<<dim3(DIM / 256, NROWS / 256, 1), blkG, 0, stream>>>(
        mid, 0, HID, w2T, 0, HID, out, 0, b2, nullptr, out, NROWS, DIM, HID, 1.0f);
}